// Round 2
// baseline (220.317 us; speedup 1.0000x reference)
//
#include <hip/hip_runtime.h>
#include <stdint.h>

// Problem constants (fixed-shape problem)
#define NN 10000   // nodes
#define NB 8       // batch
#define NF 8       // features
#define NP 12      // periods
#define NT 64      // T
#define NC 32      // C
#define KFP 96     // NF*NP
// x layout: [b][n][f][p] -> idx = b*960000 + n*96 + f*12 + p

// ---------------- small precompute: probs, Mz, Mh, cz, ch ----------------
// sm layout (floats): [0..11] probs, [16..271] Mz[f*32+c], [272..527] Mh, [528..559] cz, [560..591] ch
__global__ void k_small(const float* __restrict__ Wz, const float* __restrict__ bz,
                        const float* __restrict__ Wh, const float* __restrict__ bh,
                        const float* __restrict__ Lzw, const float* __restrict__ Lzb,
                        const float* __restrict__ Lhw, const float* __restrict__ Lhb,
                        const float* __restrict__ att, float* __restrict__ sm) {
    int t = threadIdx.x;  // 256
    int f = t >> 5, c = t & 31;
    float mz = 0.f, mh = 0.f;
    for (int j = 0; j < NC; ++j) {
        mz += Wz[f * NC + j] * Lzw[j * NC + c];
        mh += Wh[f * NC + j] * Lhw[j * NC + c];
    }
    sm[16 + t]  = mz;
    sm[272 + t] = mh;
    if (t < NC) {
        float cz = Lzb[t], ch = Lhb[t];
        for (int j = 0; j < NC; ++j) {
            cz += bz[j] * Lzw[j * NC + t];
            ch += bh[j] * Lhw[j * NC + t];
        }
        sm[528 + t] = cz;
        sm[560 + t] = ch;
    }
    if (t == 0) {
        float m = -1e30f;
        for (int p = 0; p < NP; ++p) m = fmaxf(m, att[p]);
        float e[NP]; float s = 0.f;
        for (int p = 0; p < NP; ++p) { e[p] = __expf(att[p] - m); s += e[p]; }
        for (int p = 0; p < NP; ++p) sm[p] = e[p] / s;
    }
}

// ---------------- init deg(=1 for self loop) and count(=0) ----------------
__global__ void k_init(float* __restrict__ deg, int* __restrict__ count) {
    int i = blockIdx.x * 256 + threadIdx.x;
    if (i < NN) { deg[i] = 1.0f; count[i] = 0; }
}

// ---------------- degree + in-degree histogram (edge_index is int32!) ----------------
__global__ void k_degcount(const int* __restrict__ colp, const float* __restrict__ ew,
                           float* __restrict__ deg, int* __restrict__ count, int E) {
    int e = blockIdx.x * 256 + threadIdx.x;
    if (e < E) {
        int c = colp[e];
        atomicAdd(&deg[c], ew[e]);
        atomicAdd(&count[c], 1);
    }
}

// ---------------- exclusive scan (single block) + dis = rsqrt(deg) ----------------
__global__ __launch_bounds__(1024) void k_scan(const int* __restrict__ count, const float* __restrict__ deg,
                       int* __restrict__ rowptr, int* __restrict__ cursor, float* __restrict__ dis) {
    __shared__ int part[1024];
    int tid = threadIdx.x;
    int c0 = tid * 10;
    int local[10];
    int s = 0;
    #pragma unroll
    for (int i = 0; i < 10; ++i) {
        int idx = c0 + i;
        int v = (idx < NN) ? count[idx] : 0;
        local[i] = s;
        s += v;
    }
    part[tid] = s;
    __syncthreads();
    for (int off = 1; off < 1024; off <<= 1) {
        int v = (tid >= off) ? part[tid - off] : 0;
        __syncthreads();
        part[tid] += v;
        __syncthreads();
    }
    int base = (tid > 0) ? part[tid - 1] : 0;
    #pragma unroll
    for (int i = 0; i < 10; ++i) {
        int idx = c0 + i;
        if (idx < NN) {
            int rp = base + local[i];
            rowptr[idx] = rp;
            cursor[idx] = rp;
        }
    }
    if (tid == 1023) rowptr[NN] = part[1023];
    for (int idx = tid; idx < NN; idx += 1024) dis[idx] = rsqrtf(deg[idx]);
}

// ---------------- fill CSR (by destination col), fold normalization ----------------
__global__ void k_fill(const int* __restrict__ rowp, const int* __restrict__ colp,
                       const float* __restrict__ ew, const float* __restrict__ dis,
                       int* __restrict__ cursor, int* __restrict__ csr_src, float* __restrict__ csr_w, int E) {
    int e = blockIdx.x * 256 + threadIdx.x;
    if (e < E) {
        int r = rowp[e], c = colp[e];
        float nrm = dis[r] * ew[e] * dis[c];
        int pos = atomicAdd(&cursor[c], 1);
        csr_src[pos] = r;
        csr_w[pos] = nrm;
    }
}

// ---------------- main: gather Y = Ahat @ X, GRU-collapse, attention accum, relu, lin1 ----------------
__global__ __launch_bounds__(256) void k_main(
    const float* __restrict__ x, const int* __restrict__ rowptr,
    const int* __restrict__ csr_src, const float* __restrict__ csr_w,
    const float* __restrict__ dis, const float* __restrict__ sm,
    const float* __restrict__ l1w, const float* __restrict__ l1b,
    float* __restrict__ h1g) {
    __shared__ float sMz[256], sMh[256], scz[32], sch[32], sprobs[12];
    __shared__ float sl1w[384], sl1b[12];
    __shared__ float Y[768];    // [b][k], k = f*12+p
    __shared__ float HA[256];   // [b][c]
    __shared__ int   s_src[128];
    __shared__ float s_w[128];

    const int tid = threadIdx.x;
    const int n = blockIdx.x;

    sMz[tid] = sm[16 + tid];
    sMh[tid] = sm[272 + tid];
    if (tid < 32) { scz[tid] = sm[528 + tid]; sch[tid] = sm[560 + tid]; }
    if (tid < 12) { sprobs[tid] = sm[tid]; sl1b[tid] = l1b[tid]; }
    for (int i = tid; i < 384; i += 256) sl1w[i] = l1w[i];

    // per-thread 3 accumulator slots over the 768 = [b][k] values
    const int i0 = tid, i1 = tid + 256, i2 = tid + 512;
    const int b0 = i0 / KFP, k0 = i0 % KFP;
    const int b1 = i1 / KFP, k1 = i1 % KFP;
    const int b2 = i2 / KFP, k2 = i2 % KFP;

    const float dn = dis[n];
    const float sn = dn * dn;  // self-loop norm
    float a0 = x[b0 * 960000 + n * KFP + k0] * sn;
    float a1 = x[b1 * 960000 + n * KFP + k1] * sn;
    float a2 = x[b2 * 960000 + n * KFP + k2] * sn;

    const int start = rowptr[n], end = rowptr[n + 1];
    for (int base = start; base < end; base += 128) {
        int cnt = min(128, end - base);
        __syncthreads();
        if (tid < cnt) { s_src[tid] = csr_src[base + tid]; s_w[tid] = csr_w[base + tid]; }
        __syncthreads();
        for (int q = 0; q < cnt; ++q) {
            const int soff = s_src[q] * KFP;
            const float wq = s_w[q];
            a0 = fmaf(x[b0 * 960000 + soff + k0], wq, a0);
            a1 = fmaf(x[b1 * 960000 + soff + k1], wq, a1);
            a2 = fmaf(x[b2 * 960000 + soff + k2], wq, a2);
        }
    }
    __syncthreads();
    Y[i0] = a0; Y[i1] = a1; Y[i2] = a2;
    __syncthreads();

    // GRU-collapse: thread owns (b, c)
    const int b = tid >> 5, c = tid & 31;
    float hacc = 0.f;
    #pragma unroll
    for (int p = 0; p < NP; ++p) {
        float sz = scz[c], sh = sch[c];
        #pragma unroll
        for (int f = 0; f < NF; ++f) {
            float yv = Y[b * KFP + f * NP + p];
            sz = fmaf(yv, sMz[f * 32 + c], sz);
            sh = fmaf(yv, sMh[f * 32 + c], sh);
        }
        float ez = __expf(-sz);
        float omz = 1.0f - 1.0f / (1.0f + ez);   // 1 - sigmoid(sz)
        float e2 = __expf(2.0f * sh);
        float th = 1.0f - 2.0f / (e2 + 1.0f);     // tanh(sh)
        hacc = fmaf(sprobs[p], omz * th, hacc);
    }
    HA[tid] = fmaxf(hacc, 0.f);
    __syncthreads();

    // lin1: h1[b][p] = l1b[p] + sum_c HA[b][c] * l1w[c][p];  store as h1g[(b*12+p)*NN + n]
    if (tid < 96) {
        int bb = tid / 12, p = tid % 12;
        float s = sl1b[p];
        #pragma unroll
        for (int cc = 0; cc < 32; ++cc) s = fmaf(HA[bb * 32 + cc], sl1w[cc * 12 + p], s);
        h1g[(bb * 12 + p) * NN + n] = s;
    }
}

// ---------------- init output with lin2 bias ----------------
__global__ void k_init_out(const float* __restrict__ l2b, float* __restrict__ out) {
    int i = blockIdx.x * 256 + threadIdx.x;
    if (i < NB * NT * NP) {
        int t = (i / NP) % NT;
        out[i] = l2b[t];
    }
}

// ---------------- final: out[b][t][p] += sum_n h1[b][p][n] * W2[n][t] ----------------
__global__ __launch_bounds__(256) void k_final(const float* __restrict__ h1g, const float* __restrict__ W2,
                                               float* __restrict__ out) {
    const int blk = blockIdx.x;      // b*32 + chunk
    const int b = blk >> 5, ch = blk & 31;
    const int n0 = ch * 313;
    const int n1 = min(n0 + 313, NN);
    const int t = threadIdx.x & 63, pb = threadIdx.x >> 6;  // pb in 0..3
    float acc0 = 0.f, acc1 = 0.f, acc2 = 0.f;
    for (int n = n0; n < n1; ++n) {
        float w2 = W2[n * NT + t];
        acc0 = fmaf(h1g[(b * 12 + pb) * NN + n], w2, acc0);
        acc1 = fmaf(h1g[(b * 12 + pb + 4) * NN + n], w2, acc1);
        acc2 = fmaf(h1g[(b * 12 + pb + 8) * NN + n], w2, acc2);
    }
    atomicAdd(&out[(b * NT + t) * NP + pb], acc0);
    atomicAdd(&out[(b * NT + t) * NP + pb + 4], acc1);
    atomicAdd(&out[(b * NT + t) * NP + pb + 8], acc2);
}

extern "C" void kernel_launch(void* const* d_in, const int* in_sizes, int n_in,
                              void* d_out, int out_size, void* d_ws, size_t ws_size,
                              hipStream_t stream) {
    const float* x    = (const float*)d_in[0];
    const int*   eidx = (const int*)d_in[1];   // int32 per harness convention
    const float* ew   = (const float*)d_in[2];
    const float* Wz   = (const float*)d_in[3];
    const float* bz   = (const float*)d_in[4];
    // d_in[5], d_in[6]: Wr, br (dead: H0 == 0)
    const float* Wh   = (const float*)d_in[7];
    const float* bh   = (const float*)d_in[8];
    const float* Lzw  = (const float*)d_in[9];
    const float* Lzb  = (const float*)d_in[10];
    // d_in[11], d_in[12]: Lr_w, Lr_b (dead)
    const float* Lhw  = (const float*)d_in[13];
    const float* Lhb  = (const float*)d_in[14];
    const float* att  = (const float*)d_in[15];
    const float* l1w  = (const float*)d_in[16];
    const float* l1b  = (const float*)d_in[17];
    const float* W2   = (const float*)d_in[18];
    const float* l2b  = (const float*)d_in[19];
    float* out = (float*)d_out;
    const int E = in_sizes[2];

    // workspace carve-up
    float* deg    = (float*)d_ws;
    float* dis    = deg + 10240;
    int*   count  = (int*)(dis + 10240);
    int*   rowptr = count + 10240;          // NN+1 used
    int*   cursor = rowptr + 10240;
    int*   csr_src = cursor + 10240;
    const int ER = (E + 255) & ~255;
    float* csr_w  = (float*)(csr_src + ER);
    float* sm     = csr_w + ER;             // small matrices
    float* h1g    = sm + 1024;              // 96 * 10000 floats

    const int* rowp = eidx;        // edge_index[0]
    const int* colp = eidx + E;    // edge_index[1]

    hipLaunchKernelGGL(k_small, dim3(1), dim3(256), 0, stream, Wz, bz, Wh, bh, Lzw, Lzb, Lhw, Lhb, att, sm);
    hipLaunchKernelGGL(k_init, dim3((NN + 255) / 256), dim3(256), 0, stream, deg, count);
    hipLaunchKernelGGL(k_degcount, dim3((E + 255) / 256), dim3(256), 0, stream, colp, ew, deg, count, E);
    hipLaunchKernelGGL(k_scan, dim3(1), dim3(1024), 0, stream, count, deg, rowptr, cursor, dis);
    hipLaunchKernelGGL(k_fill, dim3((E + 255) / 256), dim3(256), 0, stream, rowp, colp, ew, dis, cursor, csr_src, csr_w, E);
    hipLaunchKernelGGL(k_main, dim3(NN), dim3(256), 0, stream, x, rowptr, csr_src, csr_w, dis, sm, l1w, l1b, h1g);
    hipLaunchKernelGGL(k_init_out, dim3((NB * NT * NP + 255) / 256), dim3(256), 0, stream, l2b, out);
    hipLaunchKernelGGL(k_final, dim3(256), dim3(256), 0, stream, h1g, W2, out);
}

// Round 3
// 165.449 us; speedup vs baseline: 1.3316x; 1.3316x over previous
//
#include <hip/hip_runtime.h>
#include <stdint.h>

// Problem constants (fixed-shape problem)
#define NN 10000   // nodes
#define NB 8       // batch
#define NF 8       // features
#define NP 12      // periods
#define NT 64      // T
#define NC 32      // C
#define KFP 96     // NF*NP
#define FCH 125    // k_final chunks
#define FCN 80     // nodes per chunk (125*80 == 10000)
// x layout: [b][n][f][p] -> idx = b*960000 + n*96 + f*12 + p

// ---------------- small precompute: probs, Mz, Mh, cz, ch ----------------
// sm layout (floats): [0..11] probs, [16..271] Mz[f*32+c], [272..527] Mh, [528..559] cz, [560..591] ch
__global__ void k_small(const float* __restrict__ Wz, const float* __restrict__ bz,
                        const float* __restrict__ Wh, const float* __restrict__ bh,
                        const float* __restrict__ Lzw, const float* __restrict__ Lzb,
                        const float* __restrict__ Lhw, const float* __restrict__ Lhb,
                        const float* __restrict__ att, float* __restrict__ sm) {
    int t = threadIdx.x;  // 256
    int f = t >> 5, c = t & 31;
    float mz = 0.f, mh = 0.f;
    for (int j = 0; j < NC; ++j) {
        mz += Wz[f * NC + j] * Lzw[j * NC + c];
        mh += Wh[f * NC + j] * Lhw[j * NC + c];
    }
    sm[16 + t]  = mz;
    sm[272 + t] = mh;
    if (t < NC) {
        float cz = Lzb[t], ch = Lhb[t];
        for (int j = 0; j < NC; ++j) {
            cz += bz[j] * Lzw[j * NC + t];
            ch += bh[j] * Lhw[j * NC + t];
        }
        sm[528 + t] = cz;
        sm[560 + t] = ch;
    }
    if (t == 0) {
        float m = -1e30f;
        for (int p = 0; p < NP; ++p) m = fmaxf(m, att[p]);
        float e[NP]; float s = 0.f;
        for (int p = 0; p < NP; ++p) { e[p] = __expf(att[p] - m); s += e[p]; }
        for (int p = 0; p < NP; ++p) sm[p] = e[p] / s;
    }
}

// ---------------- init deg(=1 for self loop) and count(=0) ----------------
__global__ void k_init(float* __restrict__ deg, int* __restrict__ count) {
    int i = blockIdx.x * 256 + threadIdx.x;
    if (i < NN) { deg[i] = 1.0f; count[i] = 0; }
}

// ---------------- degree + in-degree histogram (edge_index is int32) ----------------
__global__ void k_degcount(const int* __restrict__ colp, const float* __restrict__ ew,
                           float* __restrict__ deg, int* __restrict__ count, int E) {
    int e = blockIdx.x * 256 + threadIdx.x;
    if (e < E) {
        int c = colp[e];
        atomicAdd(&deg[c], ew[e]);
        atomicAdd(&count[c], 1);
    }
}

// ---------------- exclusive scan (single block) + dis = rsqrt(deg) ----------------
__global__ __launch_bounds__(1024) void k_scan(const int* __restrict__ count, const float* __restrict__ deg,
                       int* __restrict__ rowptr, int* __restrict__ cursor, float* __restrict__ dis) {
    __shared__ int part[1024];
    int tid = threadIdx.x;
    int c0 = tid * 10;
    int local[10];
    int s = 0;
    #pragma unroll
    for (int i = 0; i < 10; ++i) {
        int idx = c0 + i;
        int v = (idx < NN) ? count[idx] : 0;
        local[i] = s;
        s += v;
    }
    part[tid] = s;
    __syncthreads();
    for (int off = 1; off < 1024; off <<= 1) {
        int v = (tid >= off) ? part[tid - off] : 0;
        __syncthreads();
        part[tid] += v;
        __syncthreads();
    }
    int base = (tid > 0) ? part[tid - 1] : 0;
    #pragma unroll
    for (int i = 0; i < 10; ++i) {
        int idx = c0 + i;
        if (idx < NN) {
            int rp = base + local[i];
            rowptr[idx] = rp;
            cursor[idx] = rp;
        }
    }
    if (tid == 1023) rowptr[NN] = part[1023];
    for (int idx = tid; idx < NN; idx += 1024) dis[idx] = rsqrtf(deg[idx]);
}

// ---------------- fill CSR (by destination col), fold normalization ----------------
__global__ void k_fill(const int* __restrict__ rowp, const int* __restrict__ colp,
                       const float* __restrict__ ew, const float* __restrict__ dis,
                       int* __restrict__ cursor, int* __restrict__ csr_src, float* __restrict__ csr_w, int E) {
    int e = blockIdx.x * 256 + threadIdx.x;
    if (e < E) {
        int r = rowp[e], c = colp[e];
        float nrm = dis[r] * ew[e] * dis[c];
        int pos = atomicAdd(&cursor[c], 1);
        csr_src[pos] = r;
        csr_w[pos] = nrm;
    }
}

// ---------------- main: gather Y = Ahat @ X, GRU-collapse, attention accum, relu, lin1 ----------------
__global__ __launch_bounds__(256) void k_main(
    const float* __restrict__ x, const int* __restrict__ rowptr,
    const int* __restrict__ csr_src, const float* __restrict__ csr_w,
    const float* __restrict__ dis, const float* __restrict__ sm,
    const float* __restrict__ l1w, const float* __restrict__ l1b,
    float* __restrict__ h1g) {
    __shared__ float sMz[256], sMh[256], scz[32], sch[32], sprobs[12];
    __shared__ float sl1w[384], sl1b[12];
    __shared__ float Y[768];    // [b][k], k = f*12+p
    __shared__ float HA[256];   // [b][c]
    __shared__ int   s_src[128];
    __shared__ float s_w[128];

    const int tid = threadIdx.x;
    const int n = blockIdx.x;

    sMz[tid] = sm[16 + tid];
    sMh[tid] = sm[272 + tid];
    if (tid < 32) { scz[tid] = sm[528 + tid]; sch[tid] = sm[560 + tid]; }
    if (tid < 12) { sprobs[tid] = sm[tid]; sl1b[tid] = l1b[tid]; }
    for (int i = tid; i < 384; i += 256) sl1w[i] = l1w[i];

    // per-thread 3 accumulator slots over the 768 = [b][k] values
    const int i0 = tid, i1 = tid + 256, i2 = tid + 512;
    const int b0 = i0 / KFP, k0 = i0 % KFP;
    const int b1 = i1 / KFP, k1 = i1 % KFP;
    const int b2 = i2 / KFP, k2 = i2 % KFP;

    const float dn = dis[n];
    const float sn = dn * dn;  // self-loop norm
    float a0 = x[b0 * 960000 + n * KFP + k0] * sn;
    float a1 = x[b1 * 960000 + n * KFP + k1] * sn;
    float a2 = x[b2 * 960000 + n * KFP + k2] * sn;

    const int start = rowptr[n], end = rowptr[n + 1];
    for (int base = start; base < end; base += 128) {
        int cnt = min(128, end - base);
        __syncthreads();
        if (tid < cnt) { s_src[tid] = csr_src[base + tid]; s_w[tid] = csr_w[base + tid]; }
        __syncthreads();
        for (int q = 0; q < cnt; ++q) {
            const int soff = s_src[q] * KFP;
            const float wq = s_w[q];
            a0 = fmaf(x[b0 * 960000 + soff + k0], wq, a0);
            a1 = fmaf(x[b1 * 960000 + soff + k1], wq, a1);
            a2 = fmaf(x[b2 * 960000 + soff + k2], wq, a2);
        }
    }
    __syncthreads();
    Y[i0] = a0; Y[i1] = a1; Y[i2] = a2;
    __syncthreads();

    // GRU-collapse: thread owns (b, c)
    const int b = tid >> 5, c = tid & 31;
    float hacc = 0.f;
    #pragma unroll
    for (int p = 0; p < NP; ++p) {
        float sz = scz[c], sh = sch[c];
        #pragma unroll
        for (int f = 0; f < NF; ++f) {
            float yv = Y[b * KFP + f * NP + p];
            sz = fmaf(yv, sMz[f * 32 + c], sz);
            sh = fmaf(yv, sMh[f * 32 + c], sh);
        }
        float ez = __expf(-sz);
        float omz = 1.0f - 1.0f / (1.0f + ez);   // 1 - sigmoid(sz)
        float e2 = __expf(2.0f * sh);
        float th = 1.0f - 2.0f / (e2 + 1.0f);     // tanh(sh)
        hacc = fmaf(sprobs[p], omz * th, hacc);
    }
    HA[tid] = fmaxf(hacc, 0.f);
    __syncthreads();

    // lin1: h1[b][p] = l1b[p] + sum_c HA[b][c] * l1w[c][p];  store as h1g[(b*12+p)*NN + n]
    if (tid < 96) {
        int bb = tid / 12, p = tid % 12;
        float s = sl1b[p];
        #pragma unroll
        for (int cc = 0; cc < 32; ++cc) s = fmaf(HA[bb * 32 + cc], sl1w[cc * 12 + p], s);
        h1g[(bb * 12 + p) * NN + n] = s;
    }
}

// ---------------- final: partial[chunk][i*64+t] = sum_{n in chunk} h1[i][n] * W2[n][t] ----------------
// i = b*12+p in [0,96). 125 blocks x 256 threads; each wave owns 24 i-values in registers.
__global__ __launch_bounds__(256) void k_final(const float* __restrict__ h1g, const float* __restrict__ W2,
                                               float* __restrict__ partial) {
    __shared__ float sh1[96 * FCN];   // 30 KB
    const int tid = threadIdx.x;
    const int n0 = blockIdx.x * FCN;

    for (int idx = tid; idx < 96 * FCN; idx += 256) {
        int i = idx / FCN, nn = idx - i * FCN;
        sh1[idx] = h1g[i * NN + n0 + nn];
    }
    __syncthreads();

    const int t = tid & 63, w = tid >> 6;      // 4 waves, each owns i in [24w, 24w+24)
    const float* sh = &sh1[w * 24 * FCN];
    float acc[24];
    #pragma unroll
    for (int j = 0; j < 24; ++j) acc[j] = 0.f;

    for (int nn = 0; nn < FCN; nn += 4) {
        const float w20 = W2[(n0 + nn + 0) * NT + t];
        const float w21 = W2[(n0 + nn + 1) * NT + t];
        const float w22 = W2[(n0 + nn + 2) * NT + t];
        const float w23 = W2[(n0 + nn + 3) * NT + t];
        #pragma unroll
        for (int j = 0; j < 24; ++j) {
            const float4 h = *(const float4*)&sh[j * FCN + nn];   // LDS broadcast, 16B aligned
            acc[j] = fmaf(h.x, w20, fmaf(h.y, w21, fmaf(h.z, w22, fmaf(h.w, w23, acc[j]))));
        }
    }

    float* pp = partial + blockIdx.x * 6144 + w * 24 * 64 + t;
    #pragma unroll
    for (int j = 0; j < 24; ++j) pp[j * 64] = acc[j];
}

// ---------------- reduce partials + lin2 bias -> out[b][t][p] ----------------
__global__ __launch_bounds__(256) void k_reduce(const float* __restrict__ partial, const float* __restrict__ l2b,
                                                float* __restrict__ out) {
    const int idx = blockIdx.x * 256 + threadIdx.x;   // 0..6143 : i*64+t
    const int i = idx >> 6, t = idx & 63;
    float s = l2b[t];
    for (int c = 0; c < FCH; ++c) s += partial[c * 6144 + idx];
    const int b = i / 12, p = i - b * 12;
    out[b * (NT * NP) + t * NP + p] = s;
}

extern "C" void kernel_launch(void* const* d_in, const int* in_sizes, int n_in,
                              void* d_out, int out_size, void* d_ws, size_t ws_size,
                              hipStream_t stream) {
    const float* x    = (const float*)d_in[0];
    const int*   eidx = (const int*)d_in[1];   // int32 per harness convention
    const float* ew   = (const float*)d_in[2];
    const float* Wz   = (const float*)d_in[3];
    const float* bz   = (const float*)d_in[4];
    // d_in[5], d_in[6]: Wr, br (dead: H0 == 0)
    const float* Wh   = (const float*)d_in[7];
    const float* bh   = (const float*)d_in[8];
    const float* Lzw  = (const float*)d_in[9];
    const float* Lzb  = (const float*)d_in[10];
    // d_in[11], d_in[12]: Lr_w, Lr_b (dead)
    const float* Lhw  = (const float*)d_in[13];
    const float* Lhb  = (const float*)d_in[14];
    const float* att  = (const float*)d_in[15];
    const float* l1w  = (const float*)d_in[16];
    const float* l1b  = (const float*)d_in[17];
    const float* W2   = (const float*)d_in[18];
    const float* l2b  = (const float*)d_in[19];
    float* out = (float*)d_out;
    const int E = in_sizes[2];

    // workspace carve-up
    float* deg    = (float*)d_ws;
    float* dis    = deg + 10240;
    int*   count  = (int*)(dis + 10240);
    int*   rowptr = count + 10240;          // NN+1 used
    int*   cursor = rowptr + 10240;
    int*   csr_src = cursor + 10240;
    const int ER = (E + 255) & ~255;
    float* csr_w  = (float*)(csr_src + ER);
    float* sm     = csr_w + ER;             // small matrices
    float* h1g    = sm + 1024;              // 96 * 10000 floats
    float* partial = h1g + 960000;          // FCH * 6144 floats = 3.07 MB

    const int* rowp = eidx;        // edge_index[0]
    const int* colp = eidx + E;    // edge_index[1]

    hipLaunchKernelGGL(k_small, dim3(1), dim3(256), 0, stream, Wz, bz, Wh, bh, Lzw, Lzb, Lhw, Lhb, att, sm);
    hipLaunchKernelGGL(k_init, dim3((NN + 255) / 256), dim3(256), 0, stream, deg, count);
    hipLaunchKernelGGL(k_degcount, dim3((E + 255) / 256), dim3(256), 0, stream, colp, ew, deg, count, E);
    hipLaunchKernelGGL(k_scan, dim3(1), dim3(1024), 0, stream, count, deg, rowptr, cursor, dis);
    hipLaunchKernelGGL(k_fill, dim3((E + 255) / 256), dim3(256), 0, stream, rowp, colp, ew, dis, cursor, csr_src, csr_w, E);
    hipLaunchKernelGGL(k_main, dim3(NN), dim3(256), 0, stream, x, rowptr, csr_src, csr_w, dis, sm, l1w, l1b, h1g);
    hipLaunchKernelGGL(k_final, dim3(FCH), dim3(256), 0, stream, h1g, W2, partial);
    hipLaunchKernelGGL(k_reduce, dim3(24), dim3(256), 0, stream, partial, l2b, out);
}